// Round 9
// baseline (1689.452 us; speedup 1.0000x reference)
//
#include <hip/hip_runtime.h>
#include <cstdint>
#include <cstddef>

// ---------------------------------------------------------------------------
// AdaAttN fused kernel set, fp16 MFMA path.
//   B=4, C=KP=512, N=M=4096.
//   ws: Fb | Gb | VT in FRAGMENT-LINEAR layouts (R11):
//     FF/GF (per batch, 2097152 f16): off = (r16*16+ks)*512 + lane*8 + j
//       holds X[i][k] with r16=i>>4, lane=(k>>3&3)*16+(i&15), ks=k>>5, j=k&7.
//     VTF (per batch, 6291456 f16):
//       off = (((mt*8+ow)*3+g)*4+ct)*2+h)*512 + lane*8 + j
//       group-g value for ch=ow*64+ct*16+(lane&15), m=mt*64+h*32+(lane>>4)*8+j
//       g: 0=v-hat, 1=fp16(v^2) hi, 2=lo residual (protects e2-mean^2).
//
// R12: occupancy 2 -> 3 waves/SIMD (single structural change vs R11).
//   R11 post-mortem: coalescing won (-35%) but MfmaUtil+VALUBusy ~= 23.6%
//   ~= Occupancy 24%: resident waves issue nearly every available cycle;
//   SIMDs idle ~76% on vmcnt/barriers. 156 regs (92+64) forces 8-wave
//   blocks to 2 waves/SIMD (1 block/CU). Fix: 4-wave blocks, QBLK=16,
//   128 ch/wave (8ct x {M,E} = 64 AGPR unchanged), launch_bounds(256,3)
//   cap 170 >= ~150 demand -> 3 blocks/CU = 12 waves/CU (37.5%).
//   Cost: V frags feed 1 rowtile (loads 14.7M -> 21M, +43%) -- free if
//   latency-bound (idle issue slots), bad if issue-bound. This round
//   discriminates the two models: <1000us => latency model; >=1150us =>
//   issue model, next step is M-tile 128 load-count reduction.
//   NOTE: every loop touching acc[]/m_run/l_run MUST be fully unrolled --
//   a runtime index demotes the array to scratch (R1/R2 bug).
//   Spill tripwire: WRITE_SIZE >> 40 MB per dispatch.
// ---------------------------------------------------------------------------

typedef _Float16 f16;
typedef _Float16 f16x8 __attribute__((ext_vector_type(8)));
typedef float f32x4 __attribute__((ext_vector_type(4)));

#define LOG2E 1.44269504088896340736f

// ---------------------------------------------------------------------------
// conv_ik: val[b][i][k] = bias[k] + sum_c wm[k][c] * in[b][c][i]
//   stored FRAGMENT-LINEAR (FF/GF layout above).
// ---------------------------------------------------------------------------
__global__ __launch_bounds__(256, 2) void conv_ik(
    const float* __restrict__ in, const float* __restrict__ wm,
    const float* __restrict__ bias, f16* __restrict__ out) {
  const int i0 = blockIdx.x * 64;
  const int k0 = blockIdx.y * 64;
  const int b = blockIdx.z;
  const int tid = threadIdx.x;
  const int lane = tid & 63;
  const int wv = tid >> 6;
  const int l15 = lane & 15;
  const int quad = lane >> 4;

  __shared__ __align__(16) f16 a_lds[64 * 40];  // [i][c] stride 40 (pad)

  const float* inb = in + (size_t)b * (512 * 4096);

  f32x4 acc[4];
#pragma unroll
  for (int t = 0; t < 4; ++t) acc[t] = f32x4{0.f, 0.f, 0.f, 0.f};

  for (int cs = 0; cs < 512; cs += 32) {
    __syncthreads();
#pragma unroll
    for (int rep = 0; rep < 2; ++rep) {
      int chunk = tid + rep * 256;  // 0..511
      int cc = chunk >> 4;          // 0..31
      int f4 = chunk & 15;          // 0..15
      float4 v = *(const float4*)(inb + (size_t)(cs + cc) * 4096 + i0 + f4 * 4);
      int ib = f4 * 4;
      a_lds[(ib + 0) * 40 + cc] = (f16)v.x;
      a_lds[(ib + 1) * 40 + cc] = (f16)v.y;
      a_lds[(ib + 2) * 40 + cc] = (f16)v.z;
      a_lds[(ib + 3) * 40 + cc] = (f16)v.w;
    }
    __syncthreads();
    f16x8 af = *(const f16x8*)&a_lds[(wv * 16 + l15) * 40 + quad * 8];
#pragma unroll
    for (int ct = 0; ct < 4; ++ct) {
      const float* wp = wm + (size_t)(k0 + ct * 16 + l15) * 512 + cs + quad * 8;
      float4 w0 = *(const float4*)wp;
      float4 w1 = *(const float4*)(wp + 4);
      f16x8 bf;
      bf[0] = (f16)w0.x; bf[1] = (f16)w0.y; bf[2] = (f16)w0.z; bf[3] = (f16)w0.w;
      bf[4] = (f16)w1.x; bf[5] = (f16)w1.y; bf[6] = (f16)w1.z; bf[7] = (f16)w1.w;
      acc[ct] = __builtin_amdgcn_mfma_f32_16x16x32_f16(af, bf, acc[ct], 0, 0, 0);
    }
  }
  f16* ob = out + (size_t)b * (4096 * 512);
#pragma unroll
  for (int ct = 0; ct < 4; ++ct) {
    int k = k0 + ct * 16 + l15;
    float bv = bias[k];
    int ks = k >> 5;
    int q = (k >> 3) & 3;
    int j = k & 7;
#pragma unroll
    for (int r = 0; r < 4; ++r) {
      int i = i0 + wv * 16 + quad * 4 + r;
      int r16 = i >> 4;
      int li = i & 15;
      ob[(size_t)(r16 * 16 + ks) * 512 + (q * 16 + li) * 8 + j] = (f16)(acc[ct][r] + bv);
    }
  }
}

// ---------------------------------------------------------------------------
// conv_vt: val = bias[k] + sum_c wm[k][c] * in[b][c][i]
//   stored FRAGMENT-LINEAR (VTF layout above): g=0 val, g=1 hi(val^2), g=2 lo.
// ---------------------------------------------------------------------------
__global__ __launch_bounds__(256, 2) void conv_vt(
    const float* __restrict__ in, const float* __restrict__ wm,
    const float* __restrict__ bias, f16* __restrict__ vt) {
  const int i0 = blockIdx.x * 64;
  const int k0 = blockIdx.y * 64;
  const int b = blockIdx.z;
  const int tid = threadIdx.x;
  const int lane = tid & 63;
  const int wv = tid >> 6;
  const int l15 = lane & 15;
  const int quad = lane >> 4;

  __shared__ __align__(16) f16 b_lds[64 * 40];  // [i][c] stride 40

  const float* inb = in + (size_t)b * (512 * 4096);

  f32x4 acc[4];
#pragma unroll
  for (int t = 0; t < 4; ++t) acc[t] = f32x4{0.f, 0.f, 0.f, 0.f};

  for (int cs = 0; cs < 512; cs += 32) {
    __syncthreads();
#pragma unroll
    for (int rep = 0; rep < 2; ++rep) {
      int chunk = tid + rep * 256;
      int cc = chunk >> 4;
      int f4 = chunk & 15;
      float4 v = *(const float4*)(inb + (size_t)(cs + cc) * 4096 + i0 + f4 * 4);
      int ib = f4 * 4;
      b_lds[(ib + 0) * 40 + cc] = (f16)v.x;
      b_lds[(ib + 1) * 40 + cc] = (f16)v.y;
      b_lds[(ib + 2) * 40 + cc] = (f16)v.z;
      b_lds[(ib + 3) * 40 + cc] = (f16)v.w;
    }
    __syncthreads();
    const float* wp = wm + (size_t)(k0 + wv * 16 + l15) * 512 + cs + quad * 8;
    float4 w0 = *(const float4*)wp;
    float4 w1 = *(const float4*)(wp + 4);
    f16x8 af;
    af[0] = (f16)w0.x; af[1] = (f16)w0.y; af[2] = (f16)w0.z; af[3] = (f16)w0.w;
    af[4] = (f16)w1.x; af[5] = (f16)w1.y; af[6] = (f16)w1.z; af[7] = (f16)w1.w;
#pragma unroll
    for (int ct = 0; ct < 4; ++ct) {
      f16x8 bfr = *(const f16x8*)&b_lds[(ct * 16 + l15) * 40 + quad * 8];
      acc[ct] = __builtin_amdgcn_mfma_f32_16x16x32_f16(af, bfr, acc[ct], 0, 0, 0);
    }
  }
  f16* vtb = vt + (size_t)b * 6291456;  // per-batch VTF
#pragma unroll
  for (int ct = 0; ct < 4; ++ct) {
    int i = i0 + ct * 16 + l15;
    int mt = i >> 6;
    int mi = i & 63;
    int h = mi >> 5;
    int q2 = (mi >> 3) & 3;
    int j = mi & 7;
#pragma unroll
    for (int r = 0; r < 4; ++r) {
      int k = k0 + wv * 16 + quad * 4 + r;
      float val = acc[ct][r] + bias[k];
      f16 vh = (f16)val;
      float vf = (float)vh;
      float sq = vf * vf;
      f16 sqh = (f16)sq;
      f16 sql = (f16)(sq - (float)sqh);
      int wvt = k >> 6;
      int ctt = (k >> 4) & 3;
      int l15t = k & 15;
      size_t o0 = (size_t)((mt * 8 + wvt) * 3) * 4096 +
                  (size_t)(ctt * 2 + h) * 512 + (q2 * 16 + l15t) * 8 + j;
      vtb[o0] = vh;             // g=0
      vtb[o0 + 4096] = sqh;     // g=1
      vtb[o0 + 8192] = sql;     // g=2
    }
  }
}

// ---------------------------------------------------------------------------
// adaattn_flash: per block = 16 Q-rows of one batch; 4 waves; M-tiles of 64.
//   QK: wave w computes logit tile cg=w (cols w*16..+16).
//   PV: wave w owns V channels [w*128,+128) = old VTF slices {2w, 2w+1}:
//       acc = 8 ct x {mean, e2} = 16 tiles = 64 AGPR; e2 hi AND lo
//       accumulate into the same accE (MFMA C is in/out).
//   All global loads contiguous 1KB wave-loads. Epilogue wave-local.
//   LDS ~2.8KB. launch_bounds(256,3): cap 170 >= ~150 -> 3 blocks/CU.
//   Grid flat 1024 blocks, XCD-batch swizzled.
// ---------------------------------------------------------------------------
__global__ __launch_bounds__(256, 3) void adaattn_flash(
    const f16* __restrict__ Fb, const f16* __restrict__ Gb,
    const f16* __restrict__ VT, const float* __restrict__ cx,
    float* __restrict__ out) {
  // --- XCD-batch swizzle: round-robin wgid->XCD (xcd = wg & 7, m09) --------
  const int wg = blockIdx.x;          // 0..1023
  const int xcd = wg & 7;             // presumed XCD id
  const int b = xcd >> 1;             // 2 XCDs per batch
  const int slot = ((xcd & 1) << 7) + (wg >> 3);  // 0..255, bijective/batch
  const int n0 = slot * 16;

  const int tid = threadIdx.x;
  const int lane = tid & 63;
  const int wv = tid >> 6;     // 0..3 == cg
  const int l15 = lane & 15;
  const int quad = lane >> 4;

  __shared__ __align__(16) f16 p_lds[16 * 72];  // [qrow 0..15][mcol] stride 72
  __shared__ float smax[64];                    // [cg][row16]
  __shared__ float ssum[64];

  // fragment-linear bases (f16 units); each load = base + lane*8 f16 = 1KB/wave
  const f16* fW = Fb + (size_t)b * 2097152 + (size_t)slot * 8192 + (size_t)lane * 8;
  const f16* gW = Gb + (size_t)b * 2097152 + (size_t)wv * 8192 + (size_t)lane * 8;
  const f16* vW = VT + (size_t)b * 6291456 + (size_t)(wv * 2) * 12288 + (size_t)lane * 8;

  f32x4 accM[8], accE[8];
#pragma unroll
  for (int t = 0; t < 8; ++t) {
    accM[t] = f32x4{0.f, 0.f, 0.f, 0.f};
    accE[t] = f32x4{0.f, 0.f, 0.f, 0.f};
  }
  float m_run[4] = {-1e30f, -1e30f, -1e30f, -1e30f};
  float l_run[4] = {0.f, 0.f, 0.f, 0.f};

  for (int m0 = 0; m0 < 4096; m0 += 64) {
    // --- QK: one 16x16 logit tile per wave (cg=wv), K=512 ------------------
    f32x4 lg = f32x4{0.f, 0.f, 0.f, 0.f};
    {
      const f16* gq = gW + (size_t)m0 * 512;  // (m0>>4)*8192
#pragma unroll 8
      for (int ks = 0; ks < 16; ++ks) {
        f16x8 gf = *(const f16x8*)(gq + ks * 512);
        f16x8 ff = *(const f16x8*)(fW + ks * 512);
        lg = __builtin_amdgcn_mfma_f32_16x16x32_f16(ff, gf, lg, 0, 0, 0);
      }
    }

    // --- wave-local row max over this wave's 16 cols (butterfly) -----------
#pragma unroll
    for (int r = 0; r < 4; ++r) {
      float v = lg[r];
      v = fmaxf(v, __shfl_xor(v, 1));
      v = fmaxf(v, __shfl_xor(v, 2));
      v = fmaxf(v, __shfl_xor(v, 4));
      v = fmaxf(v, __shfl_xor(v, 8));
      if (l15 == 0) smax[wv * 16 + quad * 4 + r] = v;
    }
    __syncthreads();  // bar1: smax complete; fences prev-iter p_lds reads

    float alpha[4], ts[4];
#pragma unroll
    for (int r = 0; r < 4; ++r) {
      int row = quad * 4 + r;
      float mt = fmaxf(fmaxf(smax[row], smax[16 + row]),
                       fmaxf(smax[32 + row], smax[48 + row]));
      float mn = fmaxf(m_run[r], mt);
      alpha[r] = exp2f((m_run[r] - mn) * LOG2E);
      m_run[r] = mn;
      float p = exp2f((lg[r] - mn) * LOG2E);
      f16 ph = (f16)p;  // round first so weights & sums agree exactly
      p = (float)ph;
      p_lds[row * 72 + wv * 16 + l15] = ph;
      float s = p;
      s += __shfl_xor(s, 1);
      s += __shfl_xor(s, 2);
      s += __shfl_xor(s, 4);
      s += __shfl_xor(s, 8);
      ts[r] = s;
    }
    if (l15 == 0) {
#pragma unroll
      for (int r = 0; r < 4; ++r) ssum[wv * 16 + quad * 4 + r] = ts[r];
    }
    // rescale accumulators by alpha (per-row); skip when all alpha == 1
    if (__any(alpha[0] != 1.f || alpha[1] != 1.f ||
              alpha[2] != 1.f || alpha[3] != 1.f)) {
#pragma unroll
      for (int t = 0; t < 8; ++t) {
#pragma unroll
        for (int r = 0; r < 4; ++r) {
          accM[t][r] *= alpha[r];
          accE[t][r] *= alpha[r];
        }
      }
    }
    __syncthreads();  // bar2: p_lds + ssum complete

#pragma unroll
    for (int r = 0; r < 4; ++r) {
      int row = quad * 4 + r;
      l_run[r] = l_run[r] * alpha[r] +
                 (ssum[row] + ssum[16 + row] + ssum[32 + row] + ssum[48 + row]);
    }

    // --- PV: A = P (LDS), B = VTF contiguous 1KB loads; per-ct loads -------
    f16x8 pf0 = *(const f16x8*)&p_lds[l15 * 72 + quad * 8];
    f16x8 pf1 = *(const f16x8*)&p_lds[l15 * 72 + 32 + quad * 8];
    const f16* vti = vW + (size_t)(m0 >> 6) * 98304;  // 8 ow-slices * 12288
#pragma unroll
    for (int ct = 0; ct < 8; ++ct) {
      const f16* vb = vti + (ct >> 2) * 12288 + (ct & 3) * 1024;
      f16x8 vm0 = *(const f16x8*)(vb);
      f16x8 vm1 = *(const f16x8*)(vb + 512);
      f16x8 vh0 = *(const f16x8*)(vb + 4096);
      f16x8 vh1 = *(const f16x8*)(vb + 4096 + 512);
      f16x8 vl0 = *(const f16x8*)(vb + 8192);
      f16x8 vl1 = *(const f16x8*)(vb + 8192 + 512);
      accM[ct] = __builtin_amdgcn_mfma_f32_16x16x32_f16(pf0, vm0, accM[ct], 0, 0, 0);
      accM[ct] = __builtin_amdgcn_mfma_f32_16x16x32_f16(pf1, vm1, accM[ct], 0, 0, 0);
      accE[ct] = __builtin_amdgcn_mfma_f32_16x16x32_f16(pf0, vh0, accE[ct], 0, 0, 0);
      accE[ct] = __builtin_amdgcn_mfma_f32_16x16x32_f16(pf1, vh1, accE[ct], 0, 0, 0);
      accE[ct] = __builtin_amdgcn_mfma_f32_16x16x32_f16(pf0, vl0, accE[ct], 0, 0, 0);
      accE[ct] = __builtin_amdgcn_mfma_f32_16x16x32_f16(pf1, vl1, accE[ct], 0, 0, 0);
    }
  }

  // ---------------- epilogue (wave-local, no LDS, no barriers) ------------
  float inv_[4];
#pragma unroll
  for (int r = 0; r < 4; ++r) inv_[r] = 1.0f / l_run[r];

  const size_t base = ((size_t)b * 512) * 4096 + n0 + quad * 4;
#pragma unroll
  for (int ct = 0; ct < 8; ++ct) {
    int c = wv * 128 + ct * 16 + l15;
    size_t off = base + (size_t)c * 4096;
    f32x4 cxv = *(const f32x4*)(cx + off);
    f32x4 o;
#pragma unroll
    for (int r = 0; r < 4; ++r) {
      float m = accM[ct][r] * inv_[r];
      float e2 = accE[ct][r] * inv_[r];
      float sd = sqrtf(fmaxf(e2 - m * m, 0.f));
      o[r] = sd * cxv[r] + m;
    }
    *(f32x4*)(out + off) = o;
  }
}

// ---------------------------------------------------------------------------
extern "C" void kernel_launch(void* const* d_in, const int* in_sizes, int n_in,
                              void* d_out, int out_size, void* d_ws, size_t ws_size,
                              hipStream_t stream) {
  (void)in_sizes; (void)n_in; (void)out_size;
  const float* c_x  = (const float*)d_in[0];
  const float* s_x  = (const float*)d_in[1];
  const float* c_1x = (const float*)d_in[2];
  const float* s_1x = (const float*)d_in[3];
  const float* f_w  = (const float*)d_in[4];
  const float* f_b  = (const float*)d_in[5];
  const float* g_w  = (const float*)d_in[6];
  const float* g_b  = (const float*)d_in[7];
  const float* h_w  = (const float*)d_in[8];
  const float* h_b  = (const float*)d_in[9];
  float* out = (float*)d_out;

  const size_t fe = (size_t)4 * 4096 * 512;  // elements per F/G buffer
  f16* Fb = (f16*)d_ws;
  f16* Gb = Fb + fe;
  f16* VT = Gb + fe;
  const size_t need = fe * 2 * sizeof(f16) * 2 + (size_t)4 * 1536 * 4096 * sizeof(f16);
  if (ws_size < need) return;  // 80 MiB required; fail loudly (output stays poisoned)

  dim3 gP(64, 8, 4);
  conv_ik<<<gP, dim3(256), 0, stream>>>(c_1x, f_w, f_b, Fb);
  conv_ik<<<gP, dim3(256), 0, stream>>>(s_1x, g_w, g_b, Gb);
  conv_vt<<<gP, dim3(256), 0, stream>>>(s_x, h_w, h_b, VT);
  adaattn_flash<<<dim3(1024), dim3(256), 0, stream>>>(Fb, Gb, VT, c_x, out);
}